// Round 3
// baseline (457.469 us; speedup 1.0000x reference)
//
#include <hip/hip_runtime.h>

#define B_ 256
#define T_ 512
#define F_ 64
#define U_ 128
#define PSTRIDE 132   // padded pool stride: bank = (4*row + col)%32, row-varying

// Butterfly sum over each aligned group of 8 lanes (VALU pipe only).
__device__ __forceinline__ float red8(float v) {
  int t;
  t = __builtin_amdgcn_update_dpp(0, __float_as_int(v), 0xB1, 0xF, 0xF, true);   // quad_perm [1,0,3,2] : xor1
  v += __int_as_float(t);
  t = __builtin_amdgcn_update_dpp(0, __float_as_int(v), 0x4E, 0xF, 0xF, true);   // quad_perm [2,3,0,1] : xor2
  v += __int_as_float(t);
  t = __builtin_amdgcn_update_dpp(0, __float_as_int(v), 0x141, 0xF, 0xF, true);  // row_half_mirror : xor4-equiv
  v += __int_as_float(t);
  return v;
}

__device__ __forceinline__ float fast_sig(float x) {
  return __builtin_amdgcn_rcpf(1.0f + __expf(-x));
}
__device__ __forceinline__ float fast_tanh(float x) {
  return fmaf(-2.0f, __builtin_amdgcn_rcpf(1.0f + __expf(2.0f * x)), 1.0f);
}

__global__ __launch_bounds__(512, 2) void grud_kernel(
    const float* __restrict__ x, const float* __restrict__ m,
    const float* __restrict__ delta_t,
    const float* __restrict__ Wz, const float* __restrict__ Uz, const float* __restrict__ bz,
    const float* __restrict__ Wr, const float* __restrict__ Ur, const float* __restrict__ br,
    const float* __restrict__ Wh, const float* __restrict__ Uh, const float* __restrict__ bh,
    const float* __restrict__ gxd, const float* __restrict__ ghd,
    const float* __restrict__ mi,
    float* __restrict__ out)
{
  const int tid = threadIdx.x;
  const int b   = blockIdx.x;
  const int kq  = tid & 7;    // k-group: k in [16kq, 16kq+16); f in [8kq, 8kq+8)
  const int ow  = tid >> 3;   // output-pair owner: u in {2ow, 2ow+1}
  const int u0  = 2 * ow;

  __shared__ float s_pool[U_ * PSTRIDE];  // 67.6 KB weight staging (reused)
  __shared__ float s_xdec[32 * F_];       // 8 KB decayed x chunk
  __shared__ float s_hist[32 * U_];       // 16 KB h outputs chunk
  __shared__ float s_hd[U_];              // h_dec
  __shared__ float s_rh[U_];              // r * h_dec
  __shared__ float s_dt[36];

  // rotated, conflict-free slot offsets (loop-invariant)
  int ho[4];
#pragma unroll
  for (int j = 0; j < 4; ++j) ho[j] = 16 * kq + 4 * (((kq >> 1) + j) & 3);

  float4 uzA[4], uzB[4], urA[4], urB[4], uhA[4], uhB[4];  // U rows, cols u0/u0+1
  float4 wzA[2], wzB[2], wrA[2], wrB[2], whA[2], whB[2];  // W rows, cols u0/u0+1

#define STAGE_MAT(SRC, ROWS)                                      \
  {                                                               \
    const float4* g4 = (const float4*)(SRC);                      \
    _Pragma("unroll") for (int i = 0; i < (ROWS) / 16; ++i) {     \
      const int e = tid + i * 512;                                \
      const int r = e >> 5, c = (e & 31) << 2;                    \
      *(float4*)(s_pool + r * PSTRIDE + c) = g4[e];               \
    }                                                             \
    __syncthreads();                                              \
  }

#define GATHER_U(DA, DB)                                          \
  _Pragma("unroll") for (int j = 0; j < 4; ++j) {                 \
    const float* p = s_pool + ho[j] * PSTRIDE + u0;               \
    DA[j] = make_float4(p[0], p[PSTRIDE], p[2 * PSTRIDE], p[3 * PSTRIDE]);         \
    DB[j] = make_float4(p[1], p[PSTRIDE + 1], p[2 * PSTRIDE + 1], p[3 * PSTRIDE + 1]); \
  }                                                               \
  __syncthreads();

#define GATHER_W(DA, DB)                                          \
  _Pragma("unroll") for (int j = 0; j < 2; ++j) {                 \
    const float* p = s_pool + (8 * kq + 4 * j) * PSTRIDE + u0;    \
    DA[j] = make_float4(p[0], p[PSTRIDE], p[2 * PSTRIDE], p[3 * PSTRIDE]);         \
    DB[j] = make_float4(p[1], p[PSTRIDE + 1], p[2 * PSTRIDE + 1], p[3 * PSTRIDE + 1]); \
  }                                                               \
  __syncthreads();

  STAGE_MAT(Uz, 128) GATHER_U(uzA, uzB)
  STAGE_MAT(Ur, 128) GATHER_U(urA, urB)
  STAGE_MAT(Uh, 128) GATHER_U(uhA, uhB)
  STAGE_MAT(Wz, 64)  GATHER_W(wzA, wzB)
  STAGE_MAT(Wr, 64)  GATHER_W(wrA, wrB)
  STAGE_MAT(Wh, 64)  GATHER_W(whA, whB)

  const float2 bz2  = ((const float2*)bz)[ow];
  const float2 br2  = ((const float2*)br)[ow];
  const float2 bh2  = ((const float2*)bh)[ow];
  float2 ghd2 = ((const float2*)ghd)[ow];
  ghd2.x = fmaxf(ghd2.x, 0.0f); ghd2.y = fmaxf(ghd2.y, 0.0f);

  if (tid < U_) s_hd[tid] = 0.0f;

  float2 hd2 = make_float2(0.0f, 0.0f);  // owned h_dec, in registers
  float zz0 = 0.0f, zz1 = 0.0f;

  for (int t0 = 0; t0 < T_; t0 += 32) {
    // ---- stage chunk: dt[33] + pre-decayed x ----
    if (tid < 33) {
      const int t = t0 + tid;
      s_dt[tid] = (t < T_) ? delta_t[b * T_ + t] : 0.0f;
    }
    {
      const int idx0 = tid * 4;
      const int tt   = idx0 >> 6;
      const int f0   = idx0 & 63;
      const float dtv = delta_t[b * T_ + t0 + tt];
      const float4 xv  = *(const float4*)(x  + (size_t)(b * T_ + t0 + tt) * F_ + f0);
      const float4 mv  = *(const float4*)(m  + (size_t)(b * T_ + t0 + tt) * F_ + f0);
      const float4 gv  = *(const float4*)(gxd + f0);
      const float4 miv = *(const float4*)(mi  + f0);
      float4 xd; float gx;
      gx   = __expf(-fmaxf(gv.x, 0.0f) * dtv);
      xd.x = mv.x * xv.x + (1.0f - mv.x) * (gx * xv.x + (1.0f - gx) * miv.x);
      gx   = __expf(-fmaxf(gv.y, 0.0f) * dtv);
      xd.y = mv.y * xv.y + (1.0f - mv.y) * (gx * xv.y + (1.0f - gx) * miv.y);
      gx   = __expf(-fmaxf(gv.z, 0.0f) * dtv);
      xd.z = mv.z * xv.z + (1.0f - mv.z) * (gx * xv.z + (1.0f - gx) * miv.z);
      gx   = __expf(-fmaxf(gv.w, 0.0f) * dtv);
      xd.w = mv.w * xv.w + (1.0f - mv.w) * (gx * xv.w + (1.0f - gx) * miv.w);
      *(float4*)(s_xdec + idx0) = xd;
    }
    __syncthreads();

#pragma unroll 4
    for (int tc = 0; tc < 32; ++tc) {
      // ---- Phase B: z, r (+ x-projections for all 3 gates) ----
      float4 h4[4];
#pragma unroll
      for (int j = 0; j < 4; ++j) h4[j] = *(const float4*)(s_hd + ho[j]);
      const float4 xa = *(const float4*)(s_xdec + tc * F_ + 8 * kq);
      const float4 xb = *(const float4*)(s_xdec + tc * F_ + 8 * kq + 4);

      float az0 = 0.f, az1 = 0.f, ar0 = 0.f, ar1 = 0.f, ah0 = 0.f, ah1 = 0.f;
#pragma unroll
      for (int j = 0; j < 4; ++j) {
        const float4 h = h4[j];
        az0 = fmaf(h.x, uzA[j].x, az0); az0 = fmaf(h.y, uzA[j].y, az0);
        az0 = fmaf(h.z, uzA[j].z, az0); az0 = fmaf(h.w, uzA[j].w, az0);
        az1 = fmaf(h.x, uzB[j].x, az1); az1 = fmaf(h.y, uzB[j].y, az1);
        az1 = fmaf(h.z, uzB[j].z, az1); az1 = fmaf(h.w, uzB[j].w, az1);
        ar0 = fmaf(h.x, urA[j].x, ar0); ar0 = fmaf(h.y, urA[j].y, ar0);
        ar0 = fmaf(h.z, urA[j].z, ar0); ar0 = fmaf(h.w, urA[j].w, ar0);
        ar1 = fmaf(h.x, urB[j].x, ar1); ar1 = fmaf(h.y, urB[j].y, ar1);
        ar1 = fmaf(h.z, urB[j].z, ar1); ar1 = fmaf(h.w, urB[j].w, ar1);
      }
      {
        az0 = fmaf(xa.x, wzA[0].x, az0); az0 = fmaf(xa.y, wzA[0].y, az0);
        az0 = fmaf(xa.z, wzA[0].z, az0); az0 = fmaf(xa.w, wzA[0].w, az0);
        az0 = fmaf(xb.x, wzA[1].x, az0); az0 = fmaf(xb.y, wzA[1].y, az0);
        az0 = fmaf(xb.z, wzA[1].z, az0); az0 = fmaf(xb.w, wzA[1].w, az0);
        az1 = fmaf(xa.x, wzB[0].x, az1); az1 = fmaf(xa.y, wzB[0].y, az1);
        az1 = fmaf(xa.z, wzB[0].z, az1); az1 = fmaf(xa.w, wzB[0].w, az1);
        az1 = fmaf(xb.x, wzB[1].x, az1); az1 = fmaf(xb.y, wzB[1].y, az1);
        az1 = fmaf(xb.z, wzB[1].z, az1); az1 = fmaf(xb.w, wzB[1].w, az1);
        ar0 = fmaf(xa.x, wrA[0].x, ar0); ar0 = fmaf(xa.y, wrA[0].y, ar0);
        ar0 = fmaf(xa.z, wrA[0].z, ar0); ar0 = fmaf(xa.w, wrA[0].w, ar0);
        ar0 = fmaf(xb.x, wrA[1].x, ar0); ar0 = fmaf(xb.y, wrA[1].y, ar0);
        ar0 = fmaf(xb.z, wrA[1].z, ar0); ar0 = fmaf(xb.w, wrA[1].w, ar0);
        ar1 = fmaf(xa.x, wrB[0].x, ar1); ar1 = fmaf(xa.y, wrB[0].y, ar1);
        ar1 = fmaf(xa.z, wrB[0].z, ar1); ar1 = fmaf(xa.w, wrB[0].w, ar1);
        ar1 = fmaf(xb.x, wrB[1].x, ar1); ar1 = fmaf(xb.y, wrB[1].y, ar1);
        ar1 = fmaf(xb.z, wrB[1].z, ar1); ar1 = fmaf(xb.w, wrB[1].w, ar1);
        ah0 = fmaf(xa.x, whA[0].x, ah0); ah0 = fmaf(xa.y, whA[0].y, ah0);
        ah0 = fmaf(xa.z, whA[0].z, ah0); ah0 = fmaf(xa.w, whA[0].w, ah0);
        ah0 = fmaf(xb.x, whA[1].x, ah0); ah0 = fmaf(xb.y, whA[1].y, ah0);
        ah0 = fmaf(xb.z, whA[1].z, ah0); ah0 = fmaf(xb.w, whA[1].w, ah0);
        ah1 = fmaf(xa.x, whB[0].x, ah1); ah1 = fmaf(xa.y, whB[0].y, ah1);
        ah1 = fmaf(xa.z, whB[0].z, ah1); ah1 = fmaf(xa.w, whB[0].w, ah1);
        ah1 = fmaf(xb.x, whB[1].x, ah1); ah1 = fmaf(xb.y, whB[1].y, ah1);
        ah1 = fmaf(xb.z, whB[1].z, ah1); ah1 = fmaf(xb.w, whB[1].w, ah1);
      }
      az0 = red8(az0); az1 = red8(az1);
      ar0 = red8(ar0); ar1 = red8(ar1);
      if (kq == 0) {
        zz0 = fast_sig(az0 + bz2.x);
        zz1 = fast_sig(az1 + bz2.y);
        const float r0 = fast_sig(ar0 + br2.x);
        const float r1 = fast_sig(ar1 + br2.y);
        *(float2*)(s_rh + u0) = make_float2(r0 * hd2.x, r1 * hd2.y);
      }
      __syncthreads();

      // ---- Phase C: candidate + update ----
      float4 r4[4];
#pragma unroll
      for (int j = 0; j < 4; ++j) r4[j] = *(const float4*)(s_rh + ho[j]);
#pragma unroll
      for (int j = 0; j < 4; ++j) {
        const float4 r = r4[j];
        ah0 = fmaf(r.x, uhA[j].x, ah0); ah0 = fmaf(r.y, uhA[j].y, ah0);
        ah0 = fmaf(r.z, uhA[j].z, ah0); ah0 = fmaf(r.w, uhA[j].w, ah0);
        ah1 = fmaf(r.x, uhB[j].x, ah1); ah1 = fmaf(r.y, uhB[j].y, ah1);
        ah1 = fmaf(r.z, uhB[j].z, ah1); ah1 = fmaf(r.w, uhB[j].w, ah1);
      }
      ah0 = red8(ah0); ah1 = red8(ah1);
      if (kq == 0) {
        const float hh0 = fast_tanh(ah0 + bh2.x);
        const float hh1 = fast_tanh(ah1 + bh2.y);
        const float hn0 = (1.0f - zz0) * hd2.x + zz0 * hh0;
        const float hn1 = (1.0f - zz1) * hd2.y + zz1 * hh1;
        *(float2*)(s_hist + tc * U_ + u0) = make_float2(hn0, hn1);
        const float dtn = s_dt[tc + 1];
        hd2.x = __expf(-ghd2.x * dtn) * hn0;
        hd2.y = __expf(-ghd2.y * dtn) * hn1;
        *(float2*)(s_hd + u0) = hd2;
      }
      __syncthreads();
    }

    // ---- flush chunk history (coalesced) ----
    {
      const float4* h4p = (const float4*)s_hist;
      float4* o4 = (float4*)(out + (size_t)(b * T_ + t0) * U_);
      o4[tid]       = h4p[tid];
      o4[tid + 512] = h4p[tid + 512];
    }
  }
}

extern "C" void kernel_launch(void* const* d_in, const int* in_sizes, int n_in,
                              void* d_out, int out_size, void* d_ws, size_t ws_size,
                              hipStream_t stream) {
  const float* x   = (const float*)d_in[0];
  const float* m   = (const float*)d_in[1];
  const float* dt  = (const float*)d_in[2];
  const float* Wz  = (const float*)d_in[3];
  const float* Uz  = (const float*)d_in[4];
  const float* bz  = (const float*)d_in[5];
  const float* Wr  = (const float*)d_in[6];
  const float* Ur  = (const float*)d_in[7];
  const float* br  = (const float*)d_in[8];
  const float* Wh  = (const float*)d_in[9];
  const float* Uh  = (const float*)d_in[10];
  const float* bh  = (const float*)d_in[11];
  const float* gxd = (const float*)d_in[12];
  const float* ghd = (const float*)d_in[13];
  const float* mi  = (const float*)d_in[14];

  grud_kernel<<<dim3(B_), dim3(512), 0, stream>>>(
      x, m, dt, Wz, Uz, bz, Wr, Ur, br, Wh, Uh, bh, gxd, ghd, mi, (float*)d_out);
}

// Round 4
// 408.461 us; speedup vs baseline: 1.1200x; 1.1200x over previous
//
#include <hip/hip_runtime.h>

#define B_ 256
#define T_ 512
#define F_ 64
#define U_ 128
#define PSTRIDE 132

typedef _Float16 h2v __attribute__((ext_vector_type(2)));
union U32H2 { unsigned u; h2v h; };

__device__ __forceinline__ float fdot2u(unsigned a, unsigned b, float c) {
#if __has_builtin(__builtin_amdgcn_fdot2)
  U32H2 x, y; x.u = a; y.u = b;
  return __builtin_amdgcn_fdot2(x.h, y.h, c, false);
#else
  U32H2 x, y; x.u = a; y.u = b;
  c = fmaf((float)x.h[0], (float)y.h[0], c);
  return fmaf((float)x.h[1], (float)y.h[1], c);
#endif
}

__device__ __forceinline__ unsigned packh2(float a, float b) {
  U32H2 r; r.h[0] = (_Float16)a; r.h[1] = (_Float16)b; return r.u;
}

// Butterfly sum over each aligned group of 8 lanes (VALU pipe only).
__device__ __forceinline__ float red8(float v) {
  int t;
  t = __builtin_amdgcn_update_dpp(0, __float_as_int(v), 0xB1, 0xF, 0xF, true);
  v += __int_as_float(t);
  t = __builtin_amdgcn_update_dpp(0, __float_as_int(v), 0x4E, 0xF, 0xF, true);
  v += __int_as_float(t);
  t = __builtin_amdgcn_update_dpp(0, __float_as_int(v), 0x141, 0xF, 0xF, true);
  v += __int_as_float(t);
  return v;
}

__device__ __forceinline__ float fast_sig(float x) {
  return __builtin_amdgcn_rcpf(1.0f + __expf(-x));
}
__device__ __forceinline__ float fast_tanh(float x) {
  return fmaf(-2.0f, __builtin_amdgcn_rcpf(1.0f + __expf(2.0f * x)), 1.0f);
}

__global__ __launch_bounds__(512, 2) void grud_kernel(
    const float* __restrict__ x, const float* __restrict__ m,
    const float* __restrict__ delta_t,
    const float* __restrict__ Wz, const float* __restrict__ Uz, const float* __restrict__ bz,
    const float* __restrict__ Wr, const float* __restrict__ Ur, const float* __restrict__ br,
    const float* __restrict__ Wh, const float* __restrict__ Uh, const float* __restrict__ bh,
    const float* __restrict__ gxd, const float* __restrict__ ghd,
    const float* __restrict__ mi,
    float* __restrict__ out)
{
  const int tid = threadIdx.x;
  const int b   = blockIdx.x;
  const int kq  = tid & 7;   // k in [16kq,16kq+16); f in [8kq,8kq+8)
  const int ow  = tid >> 3;  // outputs {2ow, 2ow+1}
  const int u0  = 2 * ow;

  // 67.6 KB pool; after setup it is re-carved into gh/hist/x16.
  __shared__ float s_mem[16896];
  float*  const s_pool = s_mem;
  float*  const s_gh   = s_mem;            // [32][128] fp32
  float*  const s_hist = s_mem + 4096;     // [32][128] fp32
  ushort* const s_x16  = (ushort*)(s_mem + 8192);  // [32][64] fp16
  __shared__ __align__(16) ushort s_hd16[U_];
  __shared__ __align__(16) ushort s_rh16[U_];
  __shared__ float s_dt[40];
  __shared__ float s_negghd[U_];

  // ---- stage + gather weights as packed fp16 pairs ----
  unsigned uz0[8], uz1[8], ur0[8], ur1[8], uh0[8], uh1[8];
  unsigned wz0[4], wz1[4], wr0[4], wr1[4], wh0[4], wh1[4];

#define STAGE_MAT(SRC, ROWS)                                      \
  {                                                               \
    const float4* g4 = (const float4*)(SRC);                      \
    _Pragma("unroll") for (int i = 0; i < (ROWS) / 16; ++i) {     \
      const int e = tid + i * 512;                                \
      const int r = e >> 5, c = (e & 31) << 2;                    \
      *(float4*)(s_pool + r * PSTRIDE + c) = g4[e];               \
    }                                                             \
    __syncthreads();                                              \
  }

#define GATHER_U(D0, D1)                                          \
  _Pragma("unroll") for (int j = 0; j < 8; ++j) {                 \
    const int k = 16 * kq + 2 * j;                                \
    D0[j] = packh2(s_pool[k * PSTRIDE + u0],                      \
                   s_pool[(k + 1) * PSTRIDE + u0]);               \
    D1[j] = packh2(s_pool[k * PSTRIDE + u0 + 1],                  \
                   s_pool[(k + 1) * PSTRIDE + u0 + 1]);           \
  }                                                               \
  __syncthreads();

#define GATHER_W(D0, D1)                                          \
  _Pragma("unroll") for (int j = 0; j < 4; ++j) {                 \
    const int f = 8 * kq + 2 * j;                                 \
    D0[j] = packh2(s_pool[f * PSTRIDE + u0],                      \
                   s_pool[(f + 1) * PSTRIDE + u0]);               \
    D1[j] = packh2(s_pool[f * PSTRIDE + u0 + 1],                  \
                   s_pool[(f + 1) * PSTRIDE + u0 + 1]);           \
  }                                                               \
  __syncthreads();

  STAGE_MAT(Uz, 128) GATHER_U(uz0, uz1)
  STAGE_MAT(Ur, 128) GATHER_U(ur0, ur1)
  STAGE_MAT(Uh, 128) GATHER_U(uh0, uh1)
  STAGE_MAT(Wz, 64)  GATHER_W(wz0, wz1)
  STAGE_MAT(Wr, 64)  GATHER_W(wr0, wr1)
  STAGE_MAT(Wh, 64)  GATHER_W(wh0, wh1)

  const float2 bz2 = ((const float2*)bz)[ow];
  const float2 br2 = ((const float2*)br)[ow];
  const float2 bh2 = ((const float2*)bh)[ow];

  if (tid < U_) {
    s_negghd[tid] = -fmaxf(ghd[tid], 0.0f);
    ((ushort*)s_hd16)[tid] = 0;   // h0 = 0 (fp16 zero)
  }

  float hd0 = 0.0f, hd1 = 0.0f;   // writer-lane h_dec (fp32)
  float z0 = 0.0f, z1 = 0.0f;

  for (int t0 = 0; t0 < T_; t0 += 32) {
    // ---- stage dt ----
    if (tid < 33) {
      const int t = t0 + tid;
      s_dt[tid] = (t < T_) ? delta_t[b * T_ + t] : 0.0f;
    }
    __syncthreads();

    // ---- stage gh table + decayed x (fp16) ----
#pragma unroll
    for (int i = 0; i < 8; ++i) {
      const int flat = tid + i * 512;       // [32][128]
      const int tcc = flat >> 7, u = flat & 127;
      s_gh[flat] = __expf(s_negghd[u] * s_dt[tcc + 1]);
    }
    {
      const int idx0 = tid * 4;             // [32][64] elements
      const int tt = idx0 >> 6, f0 = idx0 & 63;
      const float dtv = s_dt[tt];
      const float4 xv  = *(const float4*)(x  + (size_t)(b * T_ + t0 + tt) * F_ + f0);
      const float4 mv  = *(const float4*)(m  + (size_t)(b * T_ + t0 + tt) * F_ + f0);
      const float4 gv  = *(const float4*)(gxd + f0);
      const float4 miv = *(const float4*)(mi  + f0);
      float gx, d0, d1, d2, d3;
      gx = __expf(-fmaxf(gv.x, 0.0f) * dtv);
      d0 = mv.x * xv.x + (1.0f - mv.x) * (gx * xv.x + (1.0f - gx) * miv.x);
      gx = __expf(-fmaxf(gv.y, 0.0f) * dtv);
      d1 = mv.y * xv.y + (1.0f - mv.y) * (gx * xv.y + (1.0f - gx) * miv.y);
      gx = __expf(-fmaxf(gv.z, 0.0f) * dtv);
      d2 = mv.z * xv.z + (1.0f - mv.z) * (gx * xv.z + (1.0f - gx) * miv.z);
      gx = __expf(-fmaxf(gv.w, 0.0f) * dtv);
      d3 = mv.w * xv.w + (1.0f - mv.w) * (gx * xv.w + (1.0f - gx) * miv.w);
      uint2 px; px.x = packh2(d0, d1); px.y = packh2(d2, d3);
      *(uint2*)(s_x16 + idx0) = px;
    }
    __syncthreads();

#pragma unroll 4
    for (int tc = 0; tc < 32; ++tc) {
      // ---- Phase B: z, r (+ x-projections for all gates) ----
      const uint4 ha = *(const uint4*)(s_hd16 + 16 * kq);
      const uint4 hb = *(const uint4*)(s_hd16 + 16 * kq + 8);
      const uint4 xa = *(const uint4*)(s_x16 + tc * F_ + 8 * kq);

      float az0 = 0.f, az1 = 0.f, ar0 = 0.f, ar1 = 0.f, ah0 = 0.f, ah1 = 0.f;
      az0 = fdot2u(ha.x, uz0[0], az0); az0 = fdot2u(ha.y, uz0[1], az0);
      az0 = fdot2u(ha.z, uz0[2], az0); az0 = fdot2u(ha.w, uz0[3], az0);
      az0 = fdot2u(hb.x, uz0[4], az0); az0 = fdot2u(hb.y, uz0[5], az0);
      az0 = fdot2u(hb.z, uz0[6], az0); az0 = fdot2u(hb.w, uz0[7], az0);
      az1 = fdot2u(ha.x, uz1[0], az1); az1 = fdot2u(ha.y, uz1[1], az1);
      az1 = fdot2u(ha.z, uz1[2], az1); az1 = fdot2u(ha.w, uz1[3], az1);
      az1 = fdot2u(hb.x, uz1[4], az1); az1 = fdot2u(hb.y, uz1[5], az1);
      az1 = fdot2u(hb.z, uz1[6], az1); az1 = fdot2u(hb.w, uz1[7], az1);
      ar0 = fdot2u(ha.x, ur0[0], ar0); ar0 = fdot2u(ha.y, ur0[1], ar0);
      ar0 = fdot2u(ha.z, ur0[2], ar0); ar0 = fdot2u(ha.w, ur0[3], ar0);
      ar0 = fdot2u(hb.x, ur0[4], ar0); ar0 = fdot2u(hb.y, ur0[5], ar0);
      ar0 = fdot2u(hb.z, ur0[6], ar0); ar0 = fdot2u(hb.w, ur0[7], ar0);
      ar1 = fdot2u(ha.x, ur1[0], ar1); ar1 = fdot2u(ha.y, ur1[1], ar1);
      ar1 = fdot2u(ha.z, ur1[2], ar1); ar1 = fdot2u(ha.w, ur1[3], ar1);
      ar1 = fdot2u(hb.x, ur1[4], ar1); ar1 = fdot2u(hb.y, ur1[5], ar1);
      ar1 = fdot2u(hb.z, ur1[6], ar1); ar1 = fdot2u(hb.w, ur1[7], ar1);

      az0 = fdot2u(xa.x, wz0[0], az0); az0 = fdot2u(xa.y, wz0[1], az0);
      az0 = fdot2u(xa.z, wz0[2], az0); az0 = fdot2u(xa.w, wz0[3], az0);
      az1 = fdot2u(xa.x, wz1[0], az1); az1 = fdot2u(xa.y, wz1[1], az1);
      az1 = fdot2u(xa.z, wz1[2], az1); az1 = fdot2u(xa.w, wz1[3], az1);
      ar0 = fdot2u(xa.x, wr0[0], ar0); ar0 = fdot2u(xa.y, wr0[1], ar0);
      ar0 = fdot2u(xa.z, wr0[2], ar0); ar0 = fdot2u(xa.w, wr0[3], ar0);
      ar1 = fdot2u(xa.x, wr1[0], ar1); ar1 = fdot2u(xa.y, wr1[1], ar1);
      ar1 = fdot2u(xa.z, wr1[2], ar1); ar1 = fdot2u(xa.w, wr1[3], ar1);
      ah0 = fdot2u(xa.x, wh0[0], ah0); ah0 = fdot2u(xa.y, wh0[1], ah0);
      ah0 = fdot2u(xa.z, wh0[2], ah0); ah0 = fdot2u(xa.w, wh0[3], ah0);
      ah1 = fdot2u(xa.x, wh1[0], ah1); ah1 = fdot2u(xa.y, wh1[1], ah1);
      ah1 = fdot2u(xa.z, wh1[2], ah1); ah1 = fdot2u(xa.w, wh1[3], ah1);

      az0 = red8(az0); az1 = red8(az1);
      ar0 = red8(ar0); ar1 = red8(ar1);
      z0 = fast_sig(az0 + bz2.x);
      z1 = fast_sig(az1 + bz2.y);
      const float r0 = fast_sig(ar0 + br2.x);
      const float r1 = fast_sig(ar1 + br2.y);
      if (kq == 0) {
        ((unsigned*)s_rh16)[ow] = packh2(r0 * hd0, r1 * hd1);
      }
      __syncthreads();

      // ---- Phase C: candidate + update ----
      const uint4 ra = *(const uint4*)(s_rh16 + 16 * kq);
      const uint4 rb = *(const uint4*)(s_rh16 + 16 * kq + 8);
      ah0 = fdot2u(ra.x, uh0[0], ah0); ah0 = fdot2u(ra.y, uh0[1], ah0);
      ah0 = fdot2u(ra.z, uh0[2], ah0); ah0 = fdot2u(ra.w, uh0[3], ah0);
      ah0 = fdot2u(rb.x, uh0[4], ah0); ah0 = fdot2u(rb.y, uh0[5], ah0);
      ah0 = fdot2u(rb.z, uh0[6], ah0); ah0 = fdot2u(rb.w, uh0[7], ah0);
      ah1 = fdot2u(ra.x, uh1[0], ah1); ah1 = fdot2u(ra.y, uh1[1], ah1);
      ah1 = fdot2u(ra.z, uh1[2], ah1); ah1 = fdot2u(ra.w, uh1[3], ah1);
      ah1 = fdot2u(rb.x, uh1[4], ah1); ah1 = fdot2u(rb.y, uh1[5], ah1);
      ah1 = fdot2u(rb.z, uh1[6], ah1); ah1 = fdot2u(rb.w, uh1[7], ah1);
      ah0 = red8(ah0); ah1 = red8(ah1);
      if (kq == 0) {
        const float hh0 = fast_tanh(ah0 + bh2.x);
        const float hh1 = fast_tanh(ah1 + bh2.y);
        const float hn0 = fmaf(z0, hh0 - hd0, hd0);
        const float hn1 = fmaf(z1, hh1 - hd1, hd1);
        ((float2*)s_hist)[tc * 64 + ow] = make_float2(hn0, hn1);
        const float2 gh = ((const float2*)s_gh)[tc * 64 + ow];
        hd0 = gh.x * hn0;
        hd1 = gh.y * hn1;
        ((unsigned*)s_hd16)[ow] = packh2(hd0, hd1);
      }
      __syncthreads();
    }

    // ---- flush chunk history (coalesced) ----
    {
      const float4* h4p = (const float4*)s_hist;
      float4* o4 = (float4*)(out + (size_t)(b * T_ + t0) * U_);
      o4[tid]       = h4p[tid];
      o4[tid + 512] = h4p[tid + 512];
    }
    __syncthreads();
  }
}

extern "C" void kernel_launch(void* const* d_in, const int* in_sizes, int n_in,
                              void* d_out, int out_size, void* d_ws, size_t ws_size,
                              hipStream_t stream) {
  const float* x   = (const float*)d_in[0];
  const float* m   = (const float*)d_in[1];
  const float* dt  = (const float*)d_in[2];
  const float* Wz  = (const float*)d_in[3];
  const float* Uz  = (const float*)d_in[4];
  const float* bz  = (const float*)d_in[5];
  const float* Wr  = (const float*)d_in[6];
  const float* Ur  = (const float*)d_in[7];
  const float* br  = (const float*)d_in[8];
  const float* Wh  = (const float*)d_in[9];
  const float* Uh  = (const float*)d_in[10];
  const float* bh  = (const float*)d_in[11];
  const float* gxd = (const float*)d_in[12];
  const float* ghd = (const float*)d_in[13];
  const float* mi  = (const float*)d_in[14];

  grud_kernel<<<dim3(B_), dim3(512), 0, stream>>>(
      x, m, dt, Wz, Uz, bz, Wr, Ur, br, Wh, Uh, bh, gxd, ghd, mi, (float*)d_out);
}